// Round 4
// baseline (2327.567 us; speedup 1.0000x reference)
//
#include <hip/hip_runtime.h>

#define DIM 256
#define MAXNORM 0.996f      // (1 - 4e-3)/sqrt(c), c=1
#define MINN 1e-15f
#define CLIPV 0.9999999f    // 1 - 1e-7

__device__ __forceinline__ float wsum(float v) {
    v += __shfl_xor(v, 32);
    v += __shfl_xor(v, 16);
    v += __shfl_xor(v, 8);
    v += __shfl_xor(v, 4);
    v += __shfl_xor(v, 2);
    v += __shfl_xor(v, 1);
    return v;
}

// ---- marker-named kernel (zero a float buffer) — used in the real launch path ----
__global__ void HGCN_53017076302391_kernel(float* __restrict__ p, int n) {
    int i = blockIdx.x * blockDim.x + threadIdx.x;
    int stride = gridDim.x * blockDim.x;
    for (; i < n; i += stride) p[i] = 0.f;
}

// ---- stage 0: h = proj(expmap0(x)) ; one wave per row, 4 elems/lane ----
__global__ void k_expmap_in(const float* __restrict__ x,
                            float* __restrict__ out, int nrows) {
    int gid = blockIdx.x * blockDim.x + threadIdx.x;
    int row = gid >> 6, lane = gid & 63;
    if (row >= nrows) return;
    const float* xp = x + (size_t)row * DIM + lane * 4;
    float v0 = xp[0], v1 = xp[1], v2 = xp[2], v3 = xp[3];
    float ss = wsum(v0 * v0 + v1 * v1 + v2 * v2 + v3 * v3);
    float n = fmaxf(sqrtf(ss), MINN);
    float tn = tanhf(n);
    float hn = (tn > MAXNORM) ? MAXNORM : tn;
    float s = hn / n;
    float* op = out + (size_t)row * DIM + lane * 4;
    op[0] = v0 * s; op[1] = v1 * s; op[2] = v2 * s; op[3] = v3 * s;
}

// ---- bias: proj(expmap0(b)) -> bias[0..255], bias[256] = ||bias||^2 ----
__global__ void k_bias(const float* __restrict__ b, float* __restrict__ bias) {
    int lane = threadIdx.x & 63;
    if (threadIdx.x >= 64) return;
    const float* bp = b + lane * 4;
    float v0 = bp[0], v1 = bp[1], v2 = bp[2], v3 = bp[3];
    float ss = wsum(v0 * v0 + v1 * v1 + v2 * v2 + v3 * v3);
    float n = fmaxf(sqrtf(ss), MINN);
    float tn = tanhf(n);
    float hn = (tn > MAXNORM) ? MAXNORM : tn;
    float s = hn / n;
    float* o = bias + lane * 4;
    o[0] = v0 * s; o[1] = v1 * s; o[2] = v2 * s; o[3] = v3 * s;
    if (lane == 0) bias[DIM] = hn * hn;
}

// ---- GEMM: C[i][j] = sum_k A[i][k] * W[j][k]  (A fp32 M x 256, W fp32 256x256) ----
__global__ void k_gemm_bt(const float* __restrict__ A,
                          const float* __restrict__ W,
                          float* __restrict__ C, int M) {
    __shared__ float As[64][68];  // As[k][i]
    __shared__ float Bs[64][68];  // Bs[k][j] = W[j0+j][k0+k]
    const int tid = threadIdx.x;
    const int i0 = blockIdx.y * 64;
    const int j0 = blockIdx.x * 64;
    const int tx = tid & 15, ty = tid >> 4;
    float acc[4][4];
    for (int i = 0; i < 4; ++i)
        for (int j = 0; j < 4; ++j) acc[i][j] = 0.f;

    for (int k0 = 0; k0 < 256; k0 += 64) {
        for (int rep = 0; rep < 4; ++rep) {      // A tile: 64 rows x 64 fp32
            int id = rep * 256 + tid;
            int row = id >> 4, f4 = id & 15;
            int gr = i0 + row;
            float w0 = 0.f, w1 = 0.f, w2 = 0.f, w3 = 0.f;
            if (gr < M) {
                const float* ap = A + (size_t)gr * DIM + k0 + f4 * 4;
                w0 = ap[0]; w1 = ap[1]; w2 = ap[2]; w3 = ap[3];
            }
            As[f4 * 4 + 0][row] = w0;
            As[f4 * 4 + 1][row] = w1;
            As[f4 * 4 + 2][row] = w2;
            As[f4 * 4 + 3][row] = w3;
        }
        for (int rep = 0; rep < 4; ++rep) {      // B tile: 64 rows x 64 fp32
            int id = rep * 256 + tid;
            int j = id >> 4, f4 = id & 15;
            const float* wp = W + (size_t)(j0 + j) * DIM + k0 + f4 * 4;
            Bs[f4 * 4 + 0][j] = wp[0];
            Bs[f4 * 4 + 1][j] = wp[1];
            Bs[f4 * 4 + 2][j] = wp[2];
            Bs[f4 * 4 + 3][j] = wp[3];
        }
        __syncthreads();
#pragma unroll 8
        for (int k = 0; k < 64; ++k) {
            float a0 = As[k][ty * 4 + 0], a1 = As[k][ty * 4 + 1];
            float a2 = As[k][ty * 4 + 2], a3 = As[k][ty * 4 + 3];
            float b0 = Bs[k][tx * 4 + 0], b1 = Bs[k][tx * 4 + 1];
            float b2 = Bs[k][tx * 4 + 2], b3 = Bs[k][tx * 4 + 3];
            acc[0][0] = fmaf(a0, b0, acc[0][0]); acc[0][1] = fmaf(a0, b1, acc[0][1]);
            acc[0][2] = fmaf(a0, b2, acc[0][2]); acc[0][3] = fmaf(a0, b3, acc[0][3]);
            acc[1][0] = fmaf(a1, b0, acc[1][0]); acc[1][1] = fmaf(a1, b1, acc[1][1]);
            acc[1][2] = fmaf(a1, b2, acc[1][2]); acc[1][3] = fmaf(a1, b3, acc[1][3]);
            acc[2][0] = fmaf(a2, b0, acc[2][0]); acc[2][1] = fmaf(a2, b1, acc[2][1]);
            acc[2][2] = fmaf(a2, b2, acc[2][2]); acc[2][3] = fmaf(a2, b3, acc[2][3]);
            acc[3][0] = fmaf(a3, b0, acc[3][0]); acc[3][1] = fmaf(a3, b1, acc[3][1]);
            acc[3][2] = fmaf(a3, b2, acc[3][2]); acc[3][3] = fmaf(a3, b3, acc[3][3]);
        }
        __syncthreads();
    }
    for (int i = 0; i < 4; ++i) {
        int gr = i0 + ty * 4 + i;
        if (gr < M) {
            float* cp = C + (size_t)gr * DIM + j0 + tx * 4;
            cp[0] = acc[i][0]; cp[1] = acc[i][1]; cp[2] = acc[i][2]; cp[3] = acc[i][3];
        }
    }
}

// ---- fused: res=proj(mobius_matvec), mobius_add bias, proj, logmap0 -> XT ----
__global__ void k_post(const float* __restrict__ MX, const float* __restrict__ H,
                       const float* __restrict__ bias, float* __restrict__ XT, int nrows) {
    int gid = blockIdx.x * blockDim.x + threadIdx.x;
    int row = gid >> 6, lane = gid & 63;
    if (row >= nrows) return;
    size_t base = (size_t)row * DIM + lane * 4;
    const float* mp = MX + base;
    const float* hp = H + base;
    const float* bp = bias + lane * 4;
    float m0 = mp[0], m1 = mp[1], m2 = mp[2], m3 = mp[3];
    float h0 = hp[0], h1 = hp[1], h2 = hp[2], h3 = hp[3];
    float e0 = bp[0], e1 = bp[1], e2 = bp[2], e3 = bp[3];
    float sm = wsum(m0 * m0 + m1 * m1 + m2 * m2 + m3 * m3);
    float sh = wsum(h0 * h0 + h1 * h1 + h2 * h2 + h3 * h3);
    float sxy = wsum(m0 * e0 + m1 * e1 + m2 * e2 + m3 * e3);
    float y2 = bias[DIM];
    float xn = fmaxf(sqrtf(sh), MINN);
    float at = atanhf(fminf(xn, CLIPV));
    float mn = fmaxf(sqrtf(sm), MINN);
    float t = tanhf(mn / xn * at);
    float alpha = t / mn;            // res = alpha * mx
    float resn = t;
    if (t > MAXNORM) { alpha = MAXNORM / mn; resn = MAXNORM; }
    float x2 = resn * resn;
    float xy = alpha * sxy;          // res . bias
    float Aa = 1.f + 2.f * xy + y2;
    float Bb = 1.f - x2;
    float den = fmaxf(1.f + 2.f * xy + x2 * y2, MINN);
    float s_m = Aa * alpha / den;    // h = s_m*mx + s_b*bias
    float s_b = Bb / den;
    float hn2 = (Aa * Aa * x2 + 2.f * Aa * Bb * xy + Bb * Bb * y2) / (den * den);
    float hn = fmaxf(sqrtf(fmaxf(hn2, 0.f)), MINN);
    if (hn > MAXNORM) { float f = MAXNORM / hn; s_m *= f; s_b *= f; hn = MAXNORM; }
    float lt = atanhf(fminf(hn, CLIPV)) / hn;  // logmap0 scale
    s_m *= lt; s_b *= lt;
    float* op = XT + base;
    op[0] = s_m * m0 + s_b * e0;
    op[1] = s_m * m1 + s_b * e1;
    op[2] = s_m * m2 + s_b * e2;
    op[3] = s_m * m3 + s_b * e3;
}

// ---- edge scatter: agg[dst] += w * xt[src] ; one wave per edge ----
__global__ void k_scatter(const float* __restrict__ XT, const int* __restrict__ src,
                          const int* __restrict__ dst, const float* __restrict__ w,
                          float* __restrict__ AGG, int nE, int nrows) {
    int gid = blockIdx.x * blockDim.x + threadIdx.x;
    int e = gid >> 6, lane = gid & 63;
    if (e >= nE) return;
    int s = src[e], d = dst[e];
    if (s < 0 || s >= nrows || d < 0 || d >= nrows) return;
    float we = w[e];
    const float* vp = XT + (size_t)s * DIM + lane * 4;
    float* ap = AGG + (size_t)d * DIM + lane * 4;
    atomicAdd(ap + 0, we * vp[0]);
    atomicAdd(ap + 1, we * vp[1]);
    atomicAdd(ap + 2, we * vp[2]);
    atomicAdd(ap + 3, we * vp[3]);
}

// ---- finish: h=proj(expmap0(agg)); xt=relu(logmap0(h)); out=proj(expmap0(xt)) ----
__global__ void k_finish(const float* __restrict__ AGG, float* __restrict__ OUT, int nrows) {
    int gid = blockIdx.x * blockDim.x + threadIdx.x;
    int row = gid >> 6, lane = gid & 63;
    if (row >= nrows) return;
    size_t base = (size_t)row * DIM + lane * 4;
    const float* up = AGG + base;
    float u0 = up[0], u1 = up[1], u2 = up[2], u3 = up[3];
    float ss = wsum(u0 * u0 + u1 * u1 + u2 * u2 + u3 * u3);
    float n = fmaxf(sqrtf(ss), MINN);
    float tn = tanhf(n);
    float hn = (tn > MAXNORM) ? MAXNORM : tn;
    float s1 = hn / n;
    float lt = atanhf(fminf(hn, CLIPV)) / fmaxf(hn, MINN);
    float s2 = lt * s1;
    float x0 = fmaxf(s2 * u0, 0.f), x1 = fmaxf(s2 * u1, 0.f);
    float x2 = fmaxf(s2 * u2, 0.f), x3 = fmaxf(s2 * u3, 0.f);
    float ss2 = wsum(x0 * x0 + x1 * x1 + x2 * x2 + x3 * x3);
    float n2 = fmaxf(sqrtf(ss2), MINN);
    float tn2 = tanhf(n2);
    float s3 = ((tn2 > MAXNORM) ? MAXNORM : tn2) / n2;
    float* op = OUT + base;
    op[0] = s3 * x0; op[1] = s3 * x1; op[2] = s3 * x2; op[3] = s3 * x3;
}

extern "C" void kernel_launch(void* const* d_in, const int* in_sizes, int n_in,
                              void* d_out, int out_size, void* d_ws, size_t ws_size,
                              hipStream_t stream) {
    const float* x  = (const float*)d_in[0];
    const float* W1 = (const float*)d_in[1];
    const float* b1 = (const float*)d_in[2];
    const float* W2 = (const float*)d_in[3];
    const float* b2 = (const float*)d_in[4];
    const float* ew = (const float*)d_in[5];
    const int* esrc = (const int*)d_in[6];
    const int* edst = (const int*)d_in[7];
    const int nE = in_sizes[5];
    const int M  = in_sizes[0] / DIM;   // 10000

    size_t S = (size_t)M * DIM;         // floats per N x D buffer
    float* buf0 = (float*)d_ws;         // h (layer input)
    float* buf1 = buf0 + S;             // mx, then reused as agg
    float* buf2 = buf1 + S;             // xt
    float* bias = buf2 + S;             // 257 floats

    int rowBlocks = (M + 3) / 4;        // 4 waves (rows) per 256-thread block
    dim3 gemmGrid(DIM / 64, (M + 63) / 64);
    int scatBlocks = (nE + 3) / 4;

    k_expmap_in<<<rowBlocks, 256, 0, stream>>>(x, buf0, M);

    for (int layer = 0; layer < 2; ++layer) {
        const float* W = (layer == 0) ? W1 : W2;
        const float* b = (layer == 0) ? b1 : b2;
        k_bias<<<1, 64, 0, stream>>>(b, bias);
        k_gemm_bt<<<gemmGrid, 256, 0, stream>>>(buf0, W, buf1, M);
        k_post<<<rowBlocks, 256, 0, stream>>>(buf1, buf0, bias, buf2, M);
        HGCN_53017076302391_kernel<<<1024, 256, 0, stream>>>(buf1, (int)S);
        k_scatter<<<scatBlocks, 256, 0, stream>>>(buf2, esrc, edst, ew, buf1, nE, M);
        k_finish<<<rowBlocks, 256, 0, stream>>>(buf1, (layer == 0) ? buf0 : (float*)d_out, M);
    }
}

// Round 5
// 322.202 us; speedup vs baseline: 7.2239x; 7.2239x over previous
//
#include <hip/hip_runtime.h>

#define DIM 256
#define MAXNORM 0.996f      // (1 - 4e-3)/sqrt(c), c=1
#define MINN 1e-15f
#define CLIPV 0.9999999f    // 1 - 1e-7

__device__ __forceinline__ float wsum(float v) {
    v += __shfl_xor(v, 32);
    v += __shfl_xor(v, 16);
    v += __shfl_xor(v, 8);
    v += __shfl_xor(v, 4);
    v += __shfl_xor(v, 2);
    v += __shfl_xor(v, 1);
    return v;
}

// ---- stage 0: h = proj(expmap0(x)) ; one wave per row, 4 elems/lane ----
__global__ void k_expmap_in(const float* __restrict__ x,
                            float* __restrict__ out, int nrows) {
    int gid = blockIdx.x * blockDim.x + threadIdx.x;
    int row = gid >> 6, lane = gid & 63;
    if (row >= nrows) return;
    const float* xp = x + (size_t)row * DIM + lane * 4;
    float v0 = xp[0], v1 = xp[1], v2 = xp[2], v3 = xp[3];
    float ss = wsum(v0 * v0 + v1 * v1 + v2 * v2 + v3 * v3);
    float n = fmaxf(sqrtf(ss), MINN);
    float tn = tanhf(n);
    float hn = (tn > MAXNORM) ? MAXNORM : tn;
    float s = hn / n;
    float* op = out + (size_t)row * DIM + lane * 4;
    op[0] = v0 * s; op[1] = v1 * s; op[2] = v2 * s; op[3] = v3 * s;
}

// ---- bias: proj(expmap0(b)) -> bias[0..255], bias[256] = ||bias||^2 ----
__global__ void k_bias(const float* __restrict__ b, float* __restrict__ bias) {
    int lane = threadIdx.x & 63;
    if (threadIdx.x >= 64) return;
    const float* bp = b + lane * 4;
    float v0 = bp[0], v1 = bp[1], v2 = bp[2], v3 = bp[3];
    float ss = wsum(v0 * v0 + v1 * v1 + v2 * v2 + v3 * v3);
    float n = fmaxf(sqrtf(ss), MINN);
    float tn = tanhf(n);
    float hn = (tn > MAXNORM) ? MAXNORM : tn;
    float s = hn / n;
    float* o = bias + lane * 4;
    o[0] = v0 * s; o[1] = v1 * s; o[2] = v2 * s; o[3] = v3 * s;
    if (lane == 0) bias[DIM] = hn * hn;
}

// ======================= CSR build (once per call) =======================
__global__ void k_zero_int(int* __restrict__ p, int n) {
    int i = blockIdx.x * blockDim.x + threadIdx.x;
    int stride = gridDim.x * blockDim.x;
    for (; i < n; i += stride) p[i] = 0;
}

__global__ void k_hist(const int* __restrict__ dst, int* __restrict__ off, int nE, int nrows) {
    int e = blockIdx.x * blockDim.x + threadIdx.x;
    if (e >= nE) return;
    int d = dst[e];
    if (d >= 0 && d < nrows) atomicAdd(&off[d + 1], 1);
}

// single-block inclusive scan in place over a[0..n-1]
__global__ void k_scan(int* __restrict__ a, int n) {
    __shared__ int wsums[16];
    int t = threadIdx.x;                 // 1024 threads
    int chunk = (n + 1023) / 1024;
    int lo = t * chunk, hi = min(lo + chunk, n);
    int sum = 0;
    for (int i = lo; i < hi; ++i) sum += a[i];
    int lane = t & 63, wid = t >> 6;
    int v = sum;
    for (int o = 1; o < 64; o <<= 1) {
        int u = __shfl_up(v, o);
        if (lane >= o) v += u;
    }
    if (lane == 63) wsums[wid] = v;
    __syncthreads();
    if (t == 0) {
        int c = 0;
        for (int i = 0; i < 16; ++i) { int x = wsums[i]; wsums[i] = c; c += x; }
    }
    __syncthreads();
    int excl = v - sum + wsums[wid];
    int c = excl;
    for (int i = lo; i < hi; ++i) { c += a[i]; a[i] = c; }
}

__global__ void k_copy_int(const int* __restrict__ src, int* __restrict__ dst, int n) {
    int i = blockIdx.x * blockDim.x + threadIdx.x;
    int stride = gridDim.x * blockDim.x;
    for (; i < n; i += stride) dst[i] = src[i];
}

__global__ void k_fill(const int* __restrict__ esrc, const int* __restrict__ edst,
                       const float* __restrict__ ew, int* __restrict__ cursor,
                       int* __restrict__ csr_src, float* __restrict__ csr_w,
                       int nE, int nrows) {
    int e = blockIdx.x * blockDim.x + threadIdx.x;
    if (e >= nE) return;
    int d = edst[e];
    if (d < 0 || d >= nrows) return;
    int pos = atomicAdd(&cursor[d], 1);
    csr_src[pos] = esrc[e];
    csr_w[pos] = ew[e];
}

// ---- GEMM: C[i][j] = sum_k A[i][k] * W[j][k]  (A fp32 M x 256, W fp32 256x256) ----
__global__ void k_gemm_bt(const float* __restrict__ A,
                          const float* __restrict__ W,
                          float* __restrict__ C, int M) {
    __shared__ float As[64][68];  // As[k][i]
    __shared__ float Bs[64][68];  // Bs[k][j] = W[j0+j][k0+k]
    const int tid = threadIdx.x;
    const int i0 = blockIdx.y * 64;
    const int j0 = blockIdx.x * 64;
    const int tx = tid & 15, ty = tid >> 4;
    float acc[4][4];
    for (int i = 0; i < 4; ++i)
        for (int j = 0; j < 4; ++j) acc[i][j] = 0.f;

    for (int k0 = 0; k0 < 256; k0 += 64) {
        for (int rep = 0; rep < 4; ++rep) {      // A tile: 64 rows x 64 fp32
            int id = rep * 256 + tid;
            int row = id >> 4, f4 = id & 15;
            int gr = i0 + row;
            float w0 = 0.f, w1 = 0.f, w2 = 0.f, w3 = 0.f;
            if (gr < M) {
                const float* ap = A + (size_t)gr * DIM + k0 + f4 * 4;
                w0 = ap[0]; w1 = ap[1]; w2 = ap[2]; w3 = ap[3];
            }
            As[f4 * 4 + 0][row] = w0;
            As[f4 * 4 + 1][row] = w1;
            As[f4 * 4 + 2][row] = w2;
            As[f4 * 4 + 3][row] = w3;
        }
        for (int rep = 0; rep < 4; ++rep) {      // B tile: 64 rows x 64 fp32
            int id = rep * 256 + tid;
            int j = id >> 4, f4 = id & 15;
            const float* wp = W + (size_t)(j0 + j) * DIM + k0 + f4 * 4;
            Bs[f4 * 4 + 0][j] = wp[0];
            Bs[f4 * 4 + 1][j] = wp[1];
            Bs[f4 * 4 + 2][j] = wp[2];
            Bs[f4 * 4 + 3][j] = wp[3];
        }
        __syncthreads();
#pragma unroll 8
        for (int k = 0; k < 64; ++k) {
            float a0 = As[k][ty * 4 + 0], a1 = As[k][ty * 4 + 1];
            float a2 = As[k][ty * 4 + 2], a3 = As[k][ty * 4 + 3];
            float b0 = Bs[k][tx * 4 + 0], b1 = Bs[k][tx * 4 + 1];
            float b2 = Bs[k][tx * 4 + 2], b3 = Bs[k][tx * 4 + 3];
            acc[0][0] = fmaf(a0, b0, acc[0][0]); acc[0][1] = fmaf(a0, b1, acc[0][1]);
            acc[0][2] = fmaf(a0, b2, acc[0][2]); acc[0][3] = fmaf(a0, b3, acc[0][3]);
            acc[1][0] = fmaf(a1, b0, acc[1][0]); acc[1][1] = fmaf(a1, b1, acc[1][1]);
            acc[1][2] = fmaf(a1, b2, acc[1][2]); acc[1][3] = fmaf(a1, b3, acc[1][3]);
            acc[2][0] = fmaf(a2, b0, acc[2][0]); acc[2][1] = fmaf(a2, b1, acc[2][1]);
            acc[2][2] = fmaf(a2, b2, acc[2][2]); acc[2][3] = fmaf(a2, b3, acc[2][3]);
            acc[3][0] = fmaf(a3, b0, acc[3][0]); acc[3][1] = fmaf(a3, b1, acc[3][1]);
            acc[3][2] = fmaf(a3, b2, acc[3][2]); acc[3][3] = fmaf(a3, b3, acc[3][3]);
        }
        __syncthreads();
    }
    for (int i = 0; i < 4; ++i) {
        int gr = i0 + ty * 4 + i;
        if (gr < M) {
            float* cp = C + (size_t)gr * DIM + j0 + tx * 4;
            cp[0] = acc[i][0]; cp[1] = acc[i][1]; cp[2] = acc[i][2]; cp[3] = acc[i][3];
        }
    }
}

// ---- fused: res=proj(mobius_matvec), mobius_add bias, proj, logmap0 -> XT (in place over MX) ----
__global__ void k_post(const float* __restrict__ MX, const float* __restrict__ H,
                       const float* __restrict__ bias, float* __restrict__ XT, int nrows) {
    int gid = blockIdx.x * blockDim.x + threadIdx.x;
    int row = gid >> 6, lane = gid & 63;
    if (row >= nrows) return;
    size_t base = (size_t)row * DIM + lane * 4;
    const float* mp = MX + base;
    const float* hp = H + base;
    const float* bp = bias + lane * 4;
    float m0 = mp[0], m1 = mp[1], m2 = mp[2], m3 = mp[3];
    float h0 = hp[0], h1 = hp[1], h2 = hp[2], h3 = hp[3];
    float e0 = bp[0], e1 = bp[1], e2 = bp[2], e3 = bp[3];
    float sm = wsum(m0 * m0 + m1 * m1 + m2 * m2 + m3 * m3);
    float sh = wsum(h0 * h0 + h1 * h1 + h2 * h2 + h3 * h3);
    float sxy = wsum(m0 * e0 + m1 * e1 + m2 * e2 + m3 * e3);
    float y2 = bias[DIM];
    float xn = fmaxf(sqrtf(sh), MINN);
    float at = atanhf(fminf(xn, CLIPV));
    float mn = fmaxf(sqrtf(sm), MINN);
    float t = tanhf(mn / xn * at);
    float alpha = t / mn;            // res = alpha * mx
    float resn = t;
    if (t > MAXNORM) { alpha = MAXNORM / mn; resn = MAXNORM; }
    float x2 = resn * resn;
    float xy = alpha * sxy;          // res . bias
    float Aa = 1.f + 2.f * xy + y2;
    float Bb = 1.f - x2;
    float den = fmaxf(1.f + 2.f * xy + x2 * y2, MINN);
    float s_m = Aa * alpha / den;    // h = s_m*mx + s_b*bias
    float s_b = Bb / den;
    float hn2 = (Aa * Aa * x2 + 2.f * Aa * Bb * xy + Bb * Bb * y2) / (den * den);
    float hn = fmaxf(sqrtf(fmaxf(hn2, 0.f)), MINN);
    if (hn > MAXNORM) { float f = MAXNORM / hn; s_m *= f; s_b *= f; hn = MAXNORM; }
    float lt = atanhf(fminf(hn, CLIPV)) / hn;  // logmap0 scale
    s_m *= lt; s_b *= lt;
    float* op = XT + base;
    op[0] = s_m * m0 + s_b * e0;
    op[1] = s_m * m1 + s_b * e1;
    op[2] = s_m * m2 + s_b * e2;
    op[3] = s_m * m3 + s_b * e3;
}

// ---- fused CSR aggregation + finish: one wave per dst row ----
// agg = sum_e w_e * xt[src_e]; h=proj(expmap0(agg)); xt=relu(logmap0(h)); out=proj(expmap0(xt))
__global__ void k_agg_finish(const float* __restrict__ XT, const int* __restrict__ off,
                             const int* __restrict__ csrc, const float* __restrict__ cw,
                             float* __restrict__ OUT, int nrows) {
    int gid = blockIdx.x * blockDim.x + threadIdx.x;
    int row = gid >> 6, lane = gid & 63;
    if (row >= nrows) return;
    int p0 = off[row], p1 = off[row + 1];
    float a0 = 0.f, a1 = 0.f, a2 = 0.f, a3 = 0.f;
    for (int p = p0; p < p1; ++p) {
        int s = csrc[p];
        float w = cw[p];
        const float* vp = XT + (size_t)s * DIM + lane * 4;
        a0 = fmaf(w, vp[0], a0);
        a1 = fmaf(w, vp[1], a1);
        a2 = fmaf(w, vp[2], a2);
        a3 = fmaf(w, vp[3], a3);
    }
    float ss = wsum(a0 * a0 + a1 * a1 + a2 * a2 + a3 * a3);
    float n = fmaxf(sqrtf(ss), MINN);
    float tn = tanhf(n);
    float hn = (tn > MAXNORM) ? MAXNORM : tn;
    float s1 = hn / n;
    float lt = atanhf(fminf(hn, CLIPV)) / fmaxf(hn, MINN);
    float s2 = lt * s1;
    float x0 = fmaxf(s2 * a0, 0.f), x1 = fmaxf(s2 * a1, 0.f);
    float x2 = fmaxf(s2 * a2, 0.f), x3 = fmaxf(s2 * a3, 0.f);
    float ss2 = wsum(x0 * x0 + x1 * x1 + x2 * x2 + x3 * x3);
    float n2 = fmaxf(sqrtf(ss2), MINN);
    float tn2 = tanhf(n2);
    float s3 = ((tn2 > MAXNORM) ? MAXNORM : tn2) / n2;
    float* op = OUT + (size_t)row * DIM + lane * 4;
    op[0] = s3 * x0; op[1] = s3 * x1; op[2] = s3 * x2; op[3] = s3 * x3;
}

extern "C" void kernel_launch(void* const* d_in, const int* in_sizes, int n_in,
                              void* d_out, int out_size, void* d_ws, size_t ws_size,
                              hipStream_t stream) {
    const float* x  = (const float*)d_in[0];
    const float* W1 = (const float*)d_in[1];
    const float* b1 = (const float*)d_in[2];
    const float* W2 = (const float*)d_in[3];
    const float* b2 = (const float*)d_in[4];
    const float* ew = (const float*)d_in[5];
    const int* esrc = (const int*)d_in[6];
    const int* edst = (const int*)d_in[7];
    const int nE = in_sizes[5];
    const int M  = in_sizes[0] / DIM;   // 10000

    size_t S = (size_t)M * DIM;         // floats per N x D buffer
    float* buf0   = (float*)d_ws;       // h (layer input), then agg output
    float* buf1   = buf0 + S;           // mx -> xt (in place)
    float* bias   = buf1 + S;           // 260 floats (pad)
    int* csr_off  = (int*)(bias + 260); // M+1 ints
    int* cursor   = csr_off + (M + 1);  // M ints
    int* csr_src  = cursor + M;         // E ints
    float* csr_w  = (float*)(csr_src + nE); // E floats

    int rowBlocks = (M + 3) / 4;        // 4 waves (rows) per 256-thread block
    dim3 gemmGrid(DIM / 64, (M + 63) / 64);
    int edgeBlocks = (nE + 255) / 256;

    // ---- build CSR by dst (edges are call-constant) ----
    k_zero_int<<<64, 256, 0, stream>>>(csr_off, M + 1);
    k_hist<<<edgeBlocks, 256, 0, stream>>>(edst, csr_off, nE, M);
    k_scan<<<1, 1024, 0, stream>>>(csr_off, M + 1);
    k_copy_int<<<64, 256, 0, stream>>>(csr_off, cursor, M);
    k_fill<<<edgeBlocks, 256, 0, stream>>>(esrc, edst, ew, cursor, csr_src, csr_w, nE, M);

    k_expmap_in<<<rowBlocks, 256, 0, stream>>>(x, buf0, M);

    for (int layer = 0; layer < 2; ++layer) {
        const float* W = (layer == 0) ? W1 : W2;
        const float* b = (layer == 0) ? b1 : b2;
        k_bias<<<1, 64, 0, stream>>>(b, bias);
        k_gemm_bt<<<gemmGrid, 256, 0, stream>>>(buf0, W, buf1, M);
        k_post<<<rowBlocks, 256, 0, stream>>>(buf1, buf0, bias, buf1, M);
        k_agg_finish<<<rowBlocks, 256, 0, stream>>>(buf1, csr_off, csr_src, csr_w,
                                                    (layer == 0) ? buf0 : (float*)d_out, M);
    }
}

// Round 6
// 273.558 us; speedup vs baseline: 8.5085x; 1.1778x over previous
//
#include <hip/hip_runtime.h>
#include <hip/hip_fp16.h>

#define DIM 256
#define MAXNORM 0.996f      // (1 - 4e-3)/sqrt(c), c=1
#define MINN 1e-15f
#define CLIPV 0.9999999f    // 1 - 1e-7

typedef __attribute__((ext_vector_type(8))) short bf16x8;
typedef __attribute__((ext_vector_type(4))) float f32x4;

__device__ __forceinline__ unsigned short f2bf(float f) {
    unsigned int u = __float_as_uint(f);
    u += 0x7fffu + ((u >> 16) & 1u);   // RNE
    return (unsigned short)(u >> 16);
}
__device__ __forceinline__ float wsum(float v) {
    v += __shfl_xor(v, 32);
    v += __shfl_xor(v, 16);
    v += __shfl_xor(v, 8);
    v += __shfl_xor(v, 4);
    v += __shfl_xor(v, 2);
    v += __shfl_xor(v, 1);
    return v;
}

// ---- fp32 -> bf16 bulk convert ----
__global__ void k_cvt_bf16(const float* __restrict__ in, unsigned short* __restrict__ out, int n) {
    int i = blockIdx.x * blockDim.x + threadIdx.x;
    int stride = gridDim.x * blockDim.x;
    for (; i < n; i += stride) out[i] = f2bf(in[i]);
}

// ---- stage 0: h = proj(expmap0(x)) -> fp32 h + bf16 copy ----
__global__ void k_expmap_in(const float* __restrict__ x, float* __restrict__ out,
                            unsigned short* __restrict__ out_bf, int nrows) {
    int gid = blockIdx.x * blockDim.x + threadIdx.x;
    int row = gid >> 6, lane = gid & 63;
    if (row >= nrows) return;
    const float* xp = x + (size_t)row * DIM + lane * 4;
    float v0 = xp[0], v1 = xp[1], v2 = xp[2], v3 = xp[3];
    float ss = wsum(v0 * v0 + v1 * v1 + v2 * v2 + v3 * v3);
    float n = fmaxf(sqrtf(ss), MINN);
    float tn = tanhf(n);
    float hn = (tn > MAXNORM) ? MAXNORM : tn;
    float s = hn / n;
    size_t base = (size_t)row * DIM + lane * 4;
    float* op = out + base;
    op[0] = v0 * s; op[1] = v1 * s; op[2] = v2 * s; op[3] = v3 * s;
    unsigned short* ob = out_bf + base;
    ob[0] = f2bf(v0 * s); ob[1] = f2bf(v1 * s); ob[2] = f2bf(v2 * s); ob[3] = f2bf(v3 * s);
}

// ---- bias: proj(expmap0(b)) -> bias[0..255], bias[256] = ||bias||^2 ----
__global__ void k_bias(const float* __restrict__ b, float* __restrict__ bias) {
    int lane = threadIdx.x & 63;
    if (threadIdx.x >= 64) return;
    const float* bp = b + lane * 4;
    float v0 = bp[0], v1 = bp[1], v2 = bp[2], v3 = bp[3];
    float ss = wsum(v0 * v0 + v1 * v1 + v2 * v2 + v3 * v3);
    float n = fmaxf(sqrtf(ss), MINN);
    float tn = tanhf(n);
    float hn = (tn > MAXNORM) ? MAXNORM : tn;
    float s = hn / n;
    float* o = bias + lane * 4;
    o[0] = v0 * s; o[1] = v1 * s; o[2] = v2 * s; o[3] = v3 * s;
    if (lane == 0) bias[DIM] = hn * hn;
}

// ======================= CSR build (once per call) =======================
__global__ void k_zero_int(int* __restrict__ p, int n) {
    int i = blockIdx.x * blockDim.x + threadIdx.x;
    int stride = gridDim.x * blockDim.x;
    for (; i < n; i += stride) p[i] = 0;
}

__global__ void k_hist(const int* __restrict__ dst, int* __restrict__ off, int nE, int nrows) {
    int e = blockIdx.x * blockDim.x + threadIdx.x;
    if (e >= nE) return;
    int d = dst[e];
    if (d >= 0 && d < nrows) atomicAdd(&off[d + 1], 1);
}

__global__ void k_scan(int* __restrict__ a, int n) {
    __shared__ int wsums[16];
    int t = threadIdx.x;                 // 1024 threads
    int chunk = (n + 1023) / 1024;
    int lo = t * chunk, hi = min(lo + chunk, n);
    int sum = 0;
    for (int i = lo; i < hi; ++i) sum += a[i];
    int lane = t & 63, wid = t >> 6;
    int v = sum;
    for (int o = 1; o < 64; o <<= 1) {
        int u = __shfl_up(v, o);
        if (lane >= o) v += u;
    }
    if (lane == 63) wsums[wid] = v;
    __syncthreads();
    if (t == 0) {
        int c = 0;
        for (int i = 0; i < 16; ++i) { int x = wsums[i]; wsums[i] = c; c += x; }
    }
    __syncthreads();
    int excl = v - sum + wsums[wid];
    int c = excl;
    for (int i = lo; i < hi; ++i) { c += a[i]; a[i] = c; }
}

__global__ void k_copy_int(const int* __restrict__ src, int* __restrict__ dst, int n) {
    int i = blockIdx.x * blockDim.x + threadIdx.x;
    int stride = gridDim.x * blockDim.x;
    for (; i < n; i += stride) dst[i] = src[i];
}

__global__ void k_fill(const int* __restrict__ esrc, const int* __restrict__ edst,
                       const float* __restrict__ ew, int* __restrict__ cursor,
                       int* __restrict__ csr_src, float* __restrict__ csr_w,
                       int nE, int nrows) {
    int e = blockIdx.x * blockDim.x + threadIdx.x;
    if (e >= nE) return;
    int d = edst[e];
    if (d < 0 || d >= nrows) return;
    int pos = atomicAdd(&cursor[d], 1);
    csr_src[pos] = esrc[e];
    csr_w[pos] = ew[e];
}

// ---- MFMA GEMM: C[i][j] = sum_k A[i][k]*W[j][k], A/W bf16, C fp32, K=N=256 ----
// grid (16, ceil(M/64)), block 256 = 4 waves; wave computes a 16x16 tile, no LDS.
__global__ void k_gemm_mfma(const unsigned short* __restrict__ Abf,
                            const unsigned short* __restrict__ Wbf,
                            float* __restrict__ C, int M) {
    int wave = threadIdx.x >> 6;
    int lane = threadIdx.x & 63;
    int r = lane & 15, oct = lane >> 4;
    int i0 = blockIdx.y * 64 + wave * 16;
    int j0 = blockIdx.x * 16;
    int arow = i0 + r;
    bool av = arow < M;
    const unsigned short* ap = Abf + (size_t)arow * DIM + oct * 8;
    const unsigned short* bp = Wbf + (size_t)(j0 + r) * DIM + oct * 8;
    const bf16x8 zf = {0, 0, 0, 0, 0, 0, 0, 0};
    f32x4 acc = {0.f, 0.f, 0.f, 0.f};
#pragma unroll
    for (int k0 = 0; k0 < 256; k0 += 32) {
        bf16x8 a = av ? *(const bf16x8*)(ap + k0) : zf;
        bf16x8 b = *(const bf16x8*)(bp + k0);
        acc = __builtin_amdgcn_mfma_f32_16x16x32_bf16(a, b, acc, 0, 0, 0);
    }
    // C/D layout: col = lane&15, row = (lane>>4)*4 + reg
#pragma unroll
    for (int q = 0; q < 4; ++q) {
        int row = i0 + oct * 4 + q;
        if (row < M) C[(size_t)row * DIM + j0 + r] = acc[q];
    }
}

// ---- fused: res=proj(mobius_matvec), mobius_add bias, proj, logmap0 -> XT (fp16) ----
__global__ void k_post(const float* __restrict__ MX, const float* __restrict__ H,
                       const float* __restrict__ bias, __half* __restrict__ XT, int nrows) {
    int gid = blockIdx.x * blockDim.x + threadIdx.x;
    int row = gid >> 6, lane = gid & 63;
    if (row >= nrows) return;
    size_t base = (size_t)row * DIM + lane * 4;
    const float* mp = MX + base;
    const float* hp = H + base;
    const float* bp = bias + lane * 4;
    float m0 = mp[0], m1 = mp[1], m2 = mp[2], m3 = mp[3];
    float h0 = hp[0], h1 = hp[1], h2 = hp[2], h3 = hp[3];
    float e0 = bp[0], e1 = bp[1], e2 = bp[2], e3 = bp[3];
    float sm = wsum(m0 * m0 + m1 * m1 + m2 * m2 + m3 * m3);
    float sh = wsum(h0 * h0 + h1 * h1 + h2 * h2 + h3 * h3);
    float sxy = wsum(m0 * e0 + m1 * e1 + m2 * e2 + m3 * e3);
    float y2 = bias[DIM];
    float xn = fmaxf(sqrtf(sh), MINN);
    float at = atanhf(fminf(xn, CLIPV));
    float mn = fmaxf(sqrtf(sm), MINN);
    float t = tanhf(mn / xn * at);
    float alpha = t / mn;            // res = alpha * mx
    float resn = t;
    if (t > MAXNORM) { alpha = MAXNORM / mn; resn = MAXNORM; }
    float x2 = resn * resn;
    float xy = alpha * sxy;          // res . bias
    float Aa = 1.f + 2.f * xy + y2;
    float Bb = 1.f - x2;
    float den = fmaxf(1.f + 2.f * xy + x2 * y2, MINN);
    float s_m = Aa * alpha / den;    // h = s_m*mx + s_b*bias
    float s_b = Bb / den;
    float hn2 = (Aa * Aa * x2 + 2.f * Aa * Bb * xy + Bb * Bb * y2) / (den * den);
    float hn = fmaxf(sqrtf(fmaxf(hn2, 0.f)), MINN);
    if (hn > MAXNORM) { float f = MAXNORM / hn; s_m *= f; s_b *= f; hn = MAXNORM; }
    float lt = atanhf(fminf(hn, CLIPV)) / hn;  // logmap0 scale
    s_m *= lt; s_b *= lt;
    __half* op = XT + base;
    op[0] = __float2half(s_m * m0 + s_b * e0);
    op[1] = __float2half(s_m * m1 + s_b * e1);
    op[2] = __float2half(s_m * m2 + s_b * e2);
    op[3] = __float2half(s_m * m3 + s_b * e3);
}

// ---- fused CSR aggregation + finish: one wave per dst row, fp16 gather ----
__global__ void k_agg_finish(const __half* __restrict__ XT, const int* __restrict__ off,
                             const int* __restrict__ csrc, const float* __restrict__ cw,
                             float* __restrict__ OUT, unsigned short* __restrict__ OUT_bf,
                             int nrows) {
    int gid = blockIdx.x * blockDim.x + threadIdx.x;
    int row = gid >> 6, lane = gid & 63;
    if (row >= nrows) return;
    int p0 = off[row], p1 = off[row + 1];
    float a0 = 0.f, a1 = 0.f, a2 = 0.f, a3 = 0.f;
    int p = p0;
    for (; p + 1 < p1; p += 2) {
        int sA = csrc[p], sB = csrc[p + 1];
        float wA = cw[p], wB = cw[p + 1];
        const __half* vA = XT + (size_t)sA * DIM + lane * 4;
        const __half* vB = XT + (size_t)sB * DIM + lane * 4;
        float fA0 = __half2float(vA[0]), fA1 = __half2float(vA[1]);
        float fA2 = __half2float(vA[2]), fA3 = __half2float(vA[3]);
        float fB0 = __half2float(vB[0]), fB1 = __half2float(vB[1]);
        float fB2 = __half2float(vB[2]), fB3 = __half2float(vB[3]);
        a0 = fmaf(wA, fA0, a0); a1 = fmaf(wA, fA1, a1);
        a2 = fmaf(wA, fA2, a2); a3 = fmaf(wA, fA3, a3);
        a0 = fmaf(wB, fB0, a0); a1 = fmaf(wB, fB1, a1);
        a2 = fmaf(wB, fB2, a2); a3 = fmaf(wB, fB3, a3);
    }
    if (p < p1) {
        int s = csrc[p];
        float w = cw[p];
        const __half* vp = XT + (size_t)s * DIM + lane * 4;
        a0 = fmaf(w, __half2float(vp[0]), a0);
        a1 = fmaf(w, __half2float(vp[1]), a1);
        a2 = fmaf(w, __half2float(vp[2]), a2);
        a3 = fmaf(w, __half2float(vp[3]), a3);
    }
    float ss = wsum(a0 * a0 + a1 * a1 + a2 * a2 + a3 * a3);
    float n = fmaxf(sqrtf(ss), MINN);
    float tn = tanhf(n);
    float hn = (tn > MAXNORM) ? MAXNORM : tn;
    float s1 = hn / n;
    float lt = atanhf(fminf(hn, CLIPV)) / fmaxf(hn, MINN);
    float s2 = lt * s1;
    float x0 = fmaxf(s2 * a0, 0.f), x1 = fmaxf(s2 * a1, 0.f);
    float x2 = fmaxf(s2 * a2, 0.f), x3 = fmaxf(s2 * a3, 0.f);
    float ss2 = wsum(x0 * x0 + x1 * x1 + x2 * x2 + x3 * x3);
    float n2 = fmaxf(sqrtf(ss2), MINN);
    float tn2 = tanhf(n2);
    float s3 = ((tn2 > MAXNORM) ? MAXNORM : tn2) / n2;
    size_t base = (size_t)row * DIM + lane * 4;
    float* op = OUT + base;
    float o0 = s3 * x0, o1 = s3 * x1, o2 = s3 * x2, o3 = s3 * x3;
    op[0] = o0; op[1] = o1; op[2] = o2; op[3] = o3;
    if (OUT_bf) {
        unsigned short* ob = OUT_bf + base;
        ob[0] = f2bf(o0); ob[1] = f2bf(o1); ob[2] = f2bf(o2); ob[3] = f2bf(o3);
    }
}

static inline size_t align256(size_t x) { return (x + 255) & ~(size_t)255; }

extern "C" void kernel_launch(void* const* d_in, const int* in_sizes, int n_in,
                              void* d_out, int out_size, void* d_ws, size_t ws_size,
                              hipStream_t stream) {
    const float* x  = (const float*)d_in[0];
    const float* W1 = (const float*)d_in[1];
    const float* b1 = (const float*)d_in[2];
    const float* W2 = (const float*)d_in[3];
    const float* b2 = (const float*)d_in[4];
    const float* ew = (const float*)d_in[5];
    const int* esrc = (const int*)d_in[6];
    const int* edst = (const int*)d_in[7];
    const int nE = in_sizes[5];
    const int M  = in_sizes[0] / DIM;   // 10000

    size_t S = (size_t)M * DIM;         // elements per N x D buffer
    char* base = (char*)d_ws;
    size_t o = 0;
    float* h      = (float*)(base + o);          o = align256(o + S * 4);
    float* mx     = (float*)(base + o);          o = align256(o + S * 4);
    float* bias   = (float*)(base + o);          o = align256(o + 260 * 4);
    float* csr_w  = (float*)(base + o);          o = align256(o + (size_t)nE * 4);
    int* csr_off  = (int*)(base + o);            o = align256(o + (size_t)(M + 1) * 4);
    int* cursor   = (int*)(base + o);            o = align256(o + (size_t)M * 4);
    int* csr_src  = (int*)(base + o);            o = align256(o + (size_t)nE * 4);
    __half* xt    = (__half*)(base + o);         o = align256(o + S * 2);
    unsigned short* h_bf = (unsigned short*)(base + o);  o = align256(o + S * 2);
    unsigned short* w_bf = (unsigned short*)(base + o);  o = align256(o + (size_t)2 * DIM * DIM * 2);

    int rowBlocks = (M + 3) / 4;        // 4 waves (rows) per 256-thread block
    dim3 gemmGrid(DIM / 16, (M + 63) / 64);
    int edgeBlocks = (nE + 255) / 256;

    // ---- build CSR by dst (edges are call-constant) ----
    k_zero_int<<<64, 256, 0, stream>>>(csr_off, M + 1);
    k_hist<<<edgeBlocks, 256, 0, stream>>>(edst, csr_off, nE, M);
    k_scan<<<1, 1024, 0, stream>>>(csr_off, M + 1);
    k_copy_int<<<64, 256, 0, stream>>>(csr_off, cursor, M);
    k_fill<<<edgeBlocks, 256, 0, stream>>>(esrc, edst, ew, cursor, csr_src, csr_w, nE, M);

    // ---- weights to bf16 (both layers) ----
    k_cvt_bf16<<<128, 256, 0, stream>>>(W1, w_bf, DIM * DIM);
    k_cvt_bf16<<<128, 256, 0, stream>>>(W2, w_bf + DIM * DIM, DIM * DIM);

    k_expmap_in<<<rowBlocks, 256, 0, stream>>>(x, h, h_bf, M);

    for (int layer = 0; layer < 2; ++layer) {
        const float* b = (layer == 0) ? b1 : b2;
        const unsigned short* Wb = w_bf + (size_t)layer * DIM * DIM;
        k_bias<<<1, 64, 0, stream>>>(b, bias);
        k_gemm_mfma<<<gemmGrid, 256, 0, stream>>>(h_bf, Wb, mx, M);
        k_post<<<rowBlocks, 256, 0, stream>>>(mx, h, bias, xt, M);
        k_agg_finish<<<rowBlocks, 256, 0, stream>>>(xt, csr_off, csr_src, csr_w,
                                                    (layer == 0) ? h : (float*)d_out,
                                                    (layer == 0) ? h_bf : (unsigned short*)nullptr,
                                                    M);
    }
}

// Round 7
// 259.416 us; speedup vs baseline: 8.9723x; 1.0545x over previous
//
#include <hip/hip_runtime.h>
#include <hip/hip_fp16.h>

#define DIM 256
#define MAXNORM 0.996f      // (1 - 4e-3)/sqrt(c), c=1
#define MINN 1e-15f
#define CLIPV 0.9999999f    // 1 - 1e-7

typedef __attribute__((ext_vector_type(8))) short bf16x8;
typedef __attribute__((ext_vector_type(4))) float f32x4;

__device__ __forceinline__ unsigned short f2bf(float f) {
    unsigned int u = __float_as_uint(f);
    u += 0x7fffu + ((u >> 16) & 1u);   // RNE
    return (unsigned short)(u >> 16);
}
__device__ __forceinline__ float h2f(unsigned short h) {
    return __half2float(__ushort_as_half(h));
}
__device__ __forceinline__ float wsum(float v) {
    v += __shfl_xor(v, 32);
    v += __shfl_xor(v, 16);
    v += __shfl_xor(v, 8);
    v += __shfl_xor(v, 4);
    v += __shfl_xor(v, 2);
    v += __shfl_xor(v, 1);
    return v;
}

// ---- fp32 -> bf16 bulk convert, two sources in one launch ----
__global__ void k_cvt_bf16x2(const float* __restrict__ inA, const float* __restrict__ inB,
                             unsigned short* __restrict__ out, int nPer) {
    int i = blockIdx.x * blockDim.x + threadIdx.x;
    int stride = gridDim.x * blockDim.x;
    for (; i < 2 * nPer; i += stride)
        out[i] = f2bf(i < nPer ? inA[i] : inB[i - nPer]);
}

// ---- stage 0: h = proj(expmap0(x)) -> fp32 h + bf16 copy ----
__global__ void k_expmap_in(const float* __restrict__ x, float* __restrict__ out,
                            unsigned short* __restrict__ out_bf, int nrows) {
    int gid = blockIdx.x * blockDim.x + threadIdx.x;
    int row = gid >> 6, lane = gid & 63;
    if (row >= nrows) return;
    size_t base = (size_t)row * DIM + lane * 4;
    float4 v = *(const float4*)(x + base);
    float ss = wsum(v.x * v.x + v.y * v.y + v.z * v.z + v.w * v.w);
    float n = fmaxf(sqrtf(ss), MINN);
    float tn = tanhf(n);
    float hn = (tn > MAXNORM) ? MAXNORM : tn;
    float s = hn / n;
    float4 o = make_float4(v.x * s, v.y * s, v.z * s, v.w * s);
    *(float4*)(out + base) = o;
    ushort4 ob;
    ob.x = f2bf(o.x); ob.y = f2bf(o.y); ob.z = f2bf(o.z); ob.w = f2bf(o.w);
    *(ushort4*)(out_bf + base) = ob;
}

// ======================= CSR build (once per call) =======================
__global__ void k_zero_int(int* __restrict__ p, int n) {
    int i = blockIdx.x * blockDim.x + threadIdx.x;
    int stride = gridDim.x * blockDim.x;
    for (; i < n; i += stride) p[i] = 0;
}

__global__ void k_hist(const int* __restrict__ dst, int* __restrict__ off, int nE, int nrows) {
    int e = blockIdx.x * blockDim.x + threadIdx.x;
    if (e >= nE) return;
    int d = dst[e];
    if (d >= 0 && d < nrows) atomicAdd(&off[d + 1], 1);
}

// single-block inclusive scan in place over a[0..n-1]; also cursor[i]=a[i] (i<n-1)
__global__ void k_scan(int* __restrict__ a, int* __restrict__ cursor, int n) {
    __shared__ int wsums[16];
    int t = threadIdx.x;                 // 1024 threads
    int chunk = (n + 1023) / 1024;
    int lo = t * chunk, hi = min(lo + chunk, n);
    int sum = 0;
    for (int i = lo; i < hi; ++i) sum += a[i];
    int lane = t & 63, wid = t >> 6;
    int v = sum;
    for (int o = 1; o < 64; o <<= 1) {
        int u = __shfl_up(v, o);
        if (lane >= o) v += u;
    }
    if (lane == 63) wsums[wid] = v;
    __syncthreads();
    if (t == 0) {
        int c = 0;
        for (int i = 0; i < 16; ++i) { int x = wsums[i]; wsums[i] = c; c += x; }
    }
    __syncthreads();
    int excl = v - sum + wsums[wid];
    int c = excl;
    for (int i = lo; i < hi; ++i) {
        c += a[i];
        a[i] = c;
        if (i < n - 1) cursor[i] = c;
    }
}

__global__ void k_fill(const int* __restrict__ esrc, const int* __restrict__ edst,
                       const float* __restrict__ ew, int* __restrict__ cursor,
                       int* __restrict__ csr_src, float* __restrict__ csr_w,
                       int nE, int nrows) {
    int e = blockIdx.x * blockDim.x + threadIdx.x;
    if (e >= nE) return;
    int d = edst[e];
    if (d < 0 || d >= nrows) return;
    int pos = atomicAdd(&cursor[d], 1);
    csr_src[pos] = esrc[e];
    csr_w[pos] = ew[e];
}

// ---- MFMA GEMM: C[i][j] = sum_k A[i][k]*W[j][k], A/W bf16, C fp32, K=N=256 ----
// grid (16, ceil(M/64)), block 256 = 4 waves; wave computes a 16x16 tile, no LDS.
__global__ void k_gemm_mfma(const unsigned short* __restrict__ Abf,
                            const unsigned short* __restrict__ Wbf,
                            float* __restrict__ C, int M) {
    int wave = threadIdx.x >> 6;
    int lane = threadIdx.x & 63;
    int r = lane & 15, oct = lane >> 4;
    int i0 = blockIdx.y * 64 + wave * 16;
    int j0 = blockIdx.x * 16;
    int arow = i0 + r;
    bool av = arow < M;
    const unsigned short* ap = Abf + (size_t)arow * DIM + oct * 8;
    const unsigned short* bp = Wbf + (size_t)(j0 + r) * DIM + oct * 8;
    const bf16x8 zf = {0, 0, 0, 0, 0, 0, 0, 0};
    f32x4 acc = {0.f, 0.f, 0.f, 0.f};
#pragma unroll
    for (int k0 = 0; k0 < 256; k0 += 32) {
        bf16x8 a = av ? *(const bf16x8*)(ap + k0) : zf;
        bf16x8 b = *(const bf16x8*)(bp + k0);
        acc = __builtin_amdgcn_mfma_f32_16x16x32_bf16(a, b, acc, 0, 0, 0);
    }
    // C/D layout: col = lane&15, row = (lane>>4)*4 + reg
#pragma unroll
    for (int q = 0; q < 4; ++q) {
        int row = i0 + oct * 4 + q;
        if (row < M) C[(size_t)row * DIM + j0 + r] = acc[q];
    }
}

// ---- fused: bias=proj(expmap0(b)); res=proj(mobius_matvec); mobius_add; proj; logmap0 -> XT fp16 ----
__global__ void k_post(const float* __restrict__ MX, const float* __restrict__ H,
                       const float* __restrict__ b, unsigned short* __restrict__ XT, int nrows) {
    int gid = blockIdx.x * blockDim.x + threadIdx.x;
    int row = gid >> 6, lane = gid & 63;
    if (row >= nrows) return;
    size_t base = (size_t)row * DIM + lane * 4;
    float4 m = *(const float4*)(MX + base);
    float4 h = *(const float4*)(H + base);
    float4 bv = *(const float4*)(b + lane * 4);
    // bias = proj(expmap0(b)) computed per wave (cheap, removes a dispatch)
    float bs = wsum(bv.x * bv.x + bv.y * bv.y + bv.z * bv.z + bv.w * bv.w);
    float bn = fmaxf(sqrtf(bs), MINN);
    float btn = tanhf(bn);
    float bhn = (btn > MAXNORM) ? MAXNORM : btn;
    float bscale = bhn / bn;
    float e0 = bv.x * bscale, e1 = bv.y * bscale, e2 = bv.z * bscale, e3 = bv.w * bscale;
    float y2 = bhn * bhn;

    float sm = wsum(m.x * m.x + m.y * m.y + m.z * m.z + m.w * m.w);
    float sh = wsum(h.x * h.x + h.y * h.y + h.z * h.z + h.w * h.w);
    float sxy = wsum(m.x * e0 + m.y * e1 + m.z * e2 + m.w * e3);
    float xn = fmaxf(sqrtf(sh), MINN);
    float at = atanhf(fminf(xn, CLIPV));
    float mn = fmaxf(sqrtf(sm), MINN);
    float t = tanhf(mn / xn * at);
    float alpha = t / mn;            // res = alpha * mx
    float resn = t;
    if (t > MAXNORM) { alpha = MAXNORM / mn; resn = MAXNORM; }
    float x2 = resn * resn;
    float xy = alpha * sxy;          // res . bias
    float Aa = 1.f + 2.f * xy + y2;
    float Bb = 1.f - x2;
    float den = fmaxf(1.f + 2.f * xy + x2 * y2, MINN);
    float s_m = Aa * alpha / den;    // h = s_m*mx + s_b*bias
    float s_b = Bb / den;
    float hn2 = (Aa * Aa * x2 + 2.f * Aa * Bb * xy + Bb * Bb * y2) / (den * den);
    float hn = fmaxf(sqrtf(fmaxf(hn2, 0.f)), MINN);
    if (hn > MAXNORM) { float f = MAXNORM / hn; s_m *= f; s_b *= f; hn = MAXNORM; }
    float lt = atanhf(fminf(hn, CLIPV)) / hn;  // logmap0 scale
    s_m *= lt; s_b *= lt;
    ushort4 o;
    o.x = __half_as_ushort(__float2half(s_m * m.x + s_b * e0));
    o.y = __half_as_ushort(__float2half(s_m * m.y + s_b * e1));
    o.z = __half_as_ushort(__float2half(s_m * m.z + s_b * e2));
    o.w = __half_as_ushort(__float2half(s_m * m.w + s_b * e3));
    *(ushort4*)(XT + base) = o;
}

// ---- fused CSR aggregation + finish: one wave per dst row, fp16 ushort4 gather ----
__global__ void k_agg_finish(const unsigned short* __restrict__ XT, const int* __restrict__ off,
                             const int* __restrict__ csrc, const float* __restrict__ cw,
                             float* __restrict__ OUT, unsigned short* __restrict__ OUT_bf,
                             int nrows) {
    int gid = blockIdx.x * blockDim.x + threadIdx.x;
    int row = gid >> 6, lane = gid & 63;
    if (row >= nrows) return;
    int p0 = off[row], p1 = off[row + 1];
    float a0 = 0.f, a1 = 0.f, a2 = 0.f, a3 = 0.f;
    int p = p0;
    for (; p + 3 < p1; p += 4) {
        int s0 = csrc[p], s1 = csrc[p + 1], s2 = csrc[p + 2], s3 = csrc[p + 3];
        float w0 = cw[p], w1 = cw[p + 1], w2 = cw[p + 2], w3 = cw[p + 3];
        ushort4 vA = *(const ushort4*)(XT + (size_t)s0 * DIM + lane * 4);
        ushort4 vB = *(const ushort4*)(XT + (size_t)s1 * DIM + lane * 4);
        ushort4 vC = *(const ushort4*)(XT + (size_t)s2 * DIM + lane * 4);
        ushort4 vD = *(const ushort4*)(XT + (size_t)s3 * DIM + lane * 4);
        a0 = fmaf(w0, h2f(vA.x), a0); a1 = fmaf(w0, h2f(vA.y), a1);
        a2 = fmaf(w0, h2f(vA.z), a2); a3 = fmaf(w0, h2f(vA.w), a3);
        a0 = fmaf(w1, h2f(vB.x), a0); a1 = fmaf(w1, h2f(vB.y), a1);
        a2 = fmaf(w1, h2f(vB.z), a2); a3 = fmaf(w1, h2f(vB.w), a3);
        a0 = fmaf(w2, h2f(vC.x), a0); a1 = fmaf(w2, h2f(vC.y), a1);
        a2 = fmaf(w2, h2f(vC.z), a2); a3 = fmaf(w2, h2f(vC.w), a3);
        a0 = fmaf(w3, h2f(vD.x), a0); a1 = fmaf(w3, h2f(vD.y), a1);
        a2 = fmaf(w3, h2f(vD.z), a2); a3 = fmaf(w3, h2f(vD.w), a3);
    }
    for (; p < p1; ++p) {
        int s = csrc[p];
        float w = cw[p];
        ushort4 v = *(const ushort4*)(XT + (size_t)s * DIM + lane * 4);
        a0 = fmaf(w, h2f(v.x), a0); a1 = fmaf(w, h2f(v.y), a1);
        a2 = fmaf(w, h2f(v.z), a2); a3 = fmaf(w, h2f(v.w), a3);
    }
    float ss = wsum(a0 * a0 + a1 * a1 + a2 * a2 + a3 * a3);
    float n = fmaxf(sqrtf(ss), MINN);
    float tn = tanhf(n);
    float hn = (tn > MAXNORM) ? MAXNORM : tn;
    float s1 = hn / n;
    float lt = atanhf(fminf(hn, CLIPV)) / fmaxf(hn, MINN);
    float s2 = lt * s1;
    float x0 = fmaxf(s2 * a0, 0.f), x1 = fmaxf(s2 * a1, 0.f);
    float x2 = fmaxf(s2 * a2, 0.f), x3 = fmaxf(s2 * a3, 0.f);
    float ss2 = wsum(x0 * x0 + x1 * x1 + x2 * x2 + x3 * x3);
    float n2 = fmaxf(sqrtf(ss2), MINN);
    float tn2 = tanhf(n2);
    float s3 = ((tn2 > MAXNORM) ? MAXNORM : tn2) / n2;
    size_t base = (size_t)row * DIM + lane * 4;
    float o0 = s3 * x0, o1 = s3 * x1, o2 = s3 * x2, o3 = s3 * x3;
    *(float4*)(OUT + base) = make_float4(o0, o1, o2, o3);
    if (OUT_bf) {
        ushort4 ob;
        ob.x = f2bf(o0); ob.y = f2bf(o1); ob.z = f2bf(o2); ob.w = f2bf(o3);
        *(ushort4*)(OUT_bf + base) = ob;
    }
}

static inline size_t align256(size_t x) { return (x + 255) & ~(size_t)255; }

extern "C" void kernel_launch(void* const* d_in, const int* in_sizes, int n_in,
                              void* d_out, int out_size, void* d_ws, size_t ws_size,
                              hipStream_t stream) {
    const float* x  = (const float*)d_in[0];
    const float* W1 = (const float*)d_in[1];
    const float* b1 = (const float*)d_in[2];
    const float* W2 = (const float*)d_in[3];
    const float* b2 = (const float*)d_in[4];
    const float* ew = (const float*)d_in[5];
    const int* esrc = (const int*)d_in[6];
    const int* edst = (const int*)d_in[7];
    const int nE = in_sizes[5];
    const int M  = in_sizes[0] / DIM;   // 10000

    size_t S = (size_t)M * DIM;         // elements per N x D buffer
    char* base = (char*)d_ws;
    size_t o = 0;
    float* h      = (float*)(base + o);          o = align256(o + S * 4);
    float* mx     = (float*)(base + o);          o = align256(o + S * 4);
    float* csr_w  = (float*)(base + o);          o = align256(o + (size_t)nE * 4);
    int* csr_off  = (int*)(base + o);            o = align256(o + (size_t)(M + 1) * 4);
    int* cursor   = (int*)(base + o);            o = align256(o + (size_t)M * 4);
    int* csr_src  = (int*)(base + o);            o = align256(o + (size_t)nE * 4);
    unsigned short* xt   = (unsigned short*)(base + o);  o = align256(o + S * 2);
    unsigned short* h_bf = (unsigned short*)(base + o);  o = align256(o + S * 2);
    unsigned short* w_bf = (unsigned short*)(base + o);  o = align256(o + (size_t)2 * DIM * DIM * 2);

    int rowBlocks = (M + 3) / 4;        // 4 waves (rows) per 256-thread block
    dim3 gemmGrid(DIM / 16, (M + 63) / 64);
    int edgeBlocks = (nE + 255) / 256;

    // ---- build CSR by dst (edges are call-constant): 4 dispatches ----
    k_zero_int<<<64, 256, 0, stream>>>(csr_off, M + 1);
    k_hist<<<edgeBlocks, 256, 0, stream>>>(edst, csr_off, nE, M);
    k_scan<<<1, 1024, 0, stream>>>(csr_off, cursor, M + 1);
    k_fill<<<edgeBlocks, 256, 0, stream>>>(esrc, edst, ew, cursor, csr_src, csr_w, nE, M);

    // ---- weights to bf16 (both layers, one dispatch) ----
    k_cvt_bf16x2<<<256, 256, 0, stream>>>(W1, W2, w_bf, DIM * DIM);

    k_expmap_in<<<rowBlocks, 256, 0, stream>>>(x, h, h_bf, M);

    for (int layer = 0; layer < 2; ++layer) {
        const float* b = (layer == 0) ? b1 : b2;
        const unsigned short* Wb = w_bf + (size_t)layer * DIM * DIM;
        k_gemm_mfma<<<gemmGrid, 256, 0, stream>>>(h_bf, Wb, mx, M);
        k_post<<<rowBlocks, 256, 0, stream>>>(mx, h, b, xt, M);
        k_agg_finish<<<rowBlocks, 256, 0, stream>>>(xt, csr_off, csr_src, csr_w,
                                                    (layer == 0) ? h : (float*)d_out,
                                                    (layer == 0) ? h_bf : (unsigned short*)nullptr,
                                                    M);
    }
}

// Round 10
// 256.079 us; speedup vs baseline: 9.0893x; 1.0130x over previous
//
#include <hip/hip_runtime.h>
#include <hip/hip_fp16.h>

#define DIM 256
#define MAXNORM 0.996f      // (1 - 4e-3)/sqrt(c), c=1
#define MINN 1e-15f
#define CLIPV 0.9999999f    // 1 - 1e-7

typedef __attribute__((ext_vector_type(8))) short bf16x8;
typedef __attribute__((ext_vector_type(4))) float f32x4;

__device__ __forceinline__ unsigned short f2bf(float f) {
    unsigned int u = __float_as_uint(f);
    u += 0x7fffu + ((u >> 16) & 1u);   // RNE
    return (unsigned short)(u >> 16);
}
__device__ __forceinline__ float h2f(unsigned short h) {
    return __half2float(__ushort_as_half(h));
}
__device__ __forceinline__ float wsum(float v) {   // 64-lane sum
    v += __shfl_xor(v, 32);
    v += __shfl_xor(v, 16);
    v += __shfl_xor(v, 8);
    v += __shfl_xor(v, 4);
    v += __shfl_xor(v, 2);
    v += __shfl_xor(v, 1);
    return v;
}

// ---- fp32 -> bf16 bulk convert, two sources in one launch ----
__global__ void k_cvt_bf16x2(const float* __restrict__ inA, const float* __restrict__ inB,
                             unsigned short* __restrict__ out, int nPer) {
    int i = blockIdx.x * blockDim.x + threadIdx.x;
    int stride = gridDim.x * blockDim.x;
    for (; i < 2 * nPer; i += stride)
        out[i] = f2bf(i < nPer ? inA[i] : inB[i - nPer]);
}

// ---- stage 0: h = proj(expmap0(x)) -> bf16 h + |h|^2 per row ----
__global__ void k_expmap_in(const float* __restrict__ x, unsigned short* __restrict__ out_bf,
                            float* __restrict__ hnorm2, int nrows) {
    int gid = blockIdx.x * blockDim.x + threadIdx.x;
    int row = gid >> 6, lane = gid & 63;
    if (row >= nrows) return;
    size_t base = (size_t)row * DIM + lane * 4;
    float4 v = *(const float4*)(x + base);
    float ss = wsum(v.x * v.x + v.y * v.y + v.z * v.z + v.w * v.w);
    float n = fmaxf(sqrtf(ss), MINN);
    float tn = tanhf(n);
    float hn = (tn > MAXNORM) ? MAXNORM : tn;
    float s = hn / n;
    ushort4 ob;
    ob.x = f2bf(v.x * s); ob.y = f2bf(v.y * s); ob.z = f2bf(v.z * s); ob.w = f2bf(v.w * s);
    *(ushort4*)(out_bf + base) = ob;
    if (lane == 0) hnorm2[row] = hn * hn;
}

// ======================= CSR build (once per call) =======================
__global__ void k_zero_int(int* __restrict__ p, int n) {
    int i = blockIdx.x * blockDim.x + threadIdx.x;
    int stride = gridDim.x * blockDim.x;
    for (; i < n; i += stride) p[i] = 0;
}

__global__ void k_hist(const int* __restrict__ dst, int* __restrict__ off, int nE, int nrows) {
    int e = blockIdx.x * blockDim.x + threadIdx.x;
    if (e >= nE) return;
    int d = dst[e];
    if (d >= 0 && d < nrows) atomicAdd(&off[d + 1], 1);
}

// single-block inclusive scan in place over a[0..n-1]; also cursor[i]=a[i] (i<n-1)
__global__ void k_scan(int* __restrict__ a, int* __restrict__ cursor, int n) {
    __shared__ int wsums[16];
    int t = threadIdx.x;                 // 1024 threads
    int chunk = (n + 1023) / 1024;
    int lo = t * chunk, hi = min(lo + chunk, n);
    int sum = 0;
    for (int i = lo; i < hi; ++i) sum += a[i];
    int lane = t & 63, wid = t >> 6;
    int v = sum;
    for (int o = 1; o < 64; o <<= 1) {
        int u = __shfl_up(v, o);
        if (lane >= o) v += u;
    }
    if (lane == 63) wsums[wid] = v;
    __syncthreads();
    if (t == 0) {
        int c = 0;
        for (int i = 0; i < 16; ++i) { int x = wsums[i]; wsums[i] = c; c += x; }
    }
    __syncthreads();
    int excl = v - sum + wsums[wid];
    int c = excl;
    for (int i = lo; i < hi; ++i) {
        c += a[i];
        a[i] = c;
        if (i < n - 1) cursor[i] = c;
    }
}

__global__ void k_fill(const int* __restrict__ esrc, const int* __restrict__ edst,
                       const float* __restrict__ ew, int* __restrict__ cursor,
                       int* __restrict__ csr_src, float* __restrict__ csr_w,
                       int nE, int nrows) {
    int e = blockIdx.x * blockDim.x + threadIdx.x;
    if (e >= nE) return;
    int d = edst[e];
    if (d < 0 || d >= nrows) return;
    int pos = atomicAdd(&cursor[d], 1);
    csr_src[pos] = esrc[e];
    csr_w[pos] = ew[e];
}

// ---- MFMA GEMM: C[i][j] = sum_k A[i][k]*W[j][k], A/W bf16, C fp32, K=N=256 ----
// grid (16, ceil(M/64)), block 256 = 4 waves; wave computes a 16x16 tile, no LDS.
__global__ void k_gemm_mfma(const unsigned short* __restrict__ Abf,
                            const unsigned short* __restrict__ Wbf,
                            float* __restrict__ C, int M) {
    int wave = threadIdx.x >> 6;
    int lane = threadIdx.x & 63;
    int r = lane & 15, oct = lane >> 4;
    int i0 = blockIdx.y * 64 + wave * 16;
    int j0 = blockIdx.x * 16;
    int arow = i0 + r;
    bool av = arow < M;
    const unsigned short* ap = Abf + (size_t)arow * DIM + oct * 8;
    const unsigned short* bp = Wbf + (size_t)(j0 + r) * DIM + oct * 8;
    const bf16x8 zf = {0, 0, 0, 0, 0, 0, 0, 0};
    f32x4 acc = {0.f, 0.f, 0.f, 0.f};
#pragma unroll
    for (int k0 = 0; k0 < 256; k0 += 32) {
        bf16x8 a = av ? *(const bf16x8*)(ap + k0) : zf;
        bf16x8 b = *(const bf16x8*)(bp + k0);
        acc = __builtin_amdgcn_mfma_f32_16x16x32_bf16(a, b, acc, 0, 0, 0);
    }
    // C/D layout: col = lane&15, row = (lane>>4)*4 + reg
#pragma unroll
    for (int q = 0; q < 4; ++q) {
        int row = i0 + oct * 4 + q;
        if (row < M) C[(size_t)row * DIM + j0 + r] = acc[q];
    }
}

// ---- fused: bias=proj(expmap0(b)); res=proj(mobius_matvec); mobius_add; proj; logmap0 -> XT fp16 ----
// sh = |h|^2 comes from the hnorm2 side-channel (producer-computed, exact).
__global__ void k_post(const float* __restrict__ MX, const float* __restrict__ hnorm2,
                       const float* __restrict__ b, unsigned short* __restrict__ XT, int nrows) {
    int gid = blockIdx.x * blockDim.x + threadIdx.x;
    int row = gid >> 6, lane = gid & 63;
    if (row >= nrows) return;
    size_t base = (size_t)row * DIM + lane * 4;
    float4 m = *(const float4*)(MX + base);
    float4 bv = *(const float4*)(b + lane * 4);
    // bias = proj(expmap0(b)) computed per wave (cheap)
    float bs = wsum(bv.x * bv.x + bv.y * bv.y + bv.z * bv.z + bv.w * bv.w);
    float bn = fmaxf(sqrtf(bs), MINN);
    float btn = tanhf(bn);
    float bhn = (btn > MAXNORM) ? MAXNORM : btn;
    float bscale = bhn / bn;
    float e0 = bv.x * bscale, e1 = bv.y * bscale, e2 = bv.z * bscale, e3 = bv.w * bscale;
    float y2 = bhn * bhn;

    float sm = wsum(m.x * m.x + m.y * m.y + m.z * m.z + m.w * m.w);
    float sxy = wsum(m.x * e0 + m.y * e1 + m.z * e2 + m.w * e3);
    float sh = hnorm2[row];
    float xn = fmaxf(sqrtf(sh), MINN);
    float at = atanhf(fminf(xn, CLIPV));
    float mn = fmaxf(sqrtf(sm), MINN);
    float t = tanhf(mn / xn * at);
    float alpha = t / mn;            // res = alpha * mx
    float resn = t;
    if (t > MAXNORM) { alpha = MAXNORM / mn; resn = MAXNORM; }
    float x2 = resn * resn;
    float xy = alpha * sxy;          // res . bias
    float Aa = 1.f + 2.f * xy + y2;
    float Bb = 1.f - x2;
    float den = fmaxf(1.f + 2.f * xy + x2 * y2, MINN);
    float s_m = Aa * alpha / den;    // h = s_m*mx + s_b*bias
    float s_b = Bb / den;
    float hn2 = (Aa * Aa * x2 + 2.f * Aa * Bb * xy + Bb * Bb * y2) / (den * den);
    float hn = fmaxf(sqrtf(fmaxf(hn2, 0.f)), MINN);
    if (hn > MAXNORM) { float f = MAXNORM / hn; s_m *= f; s_b *= f; hn = MAXNORM; }
    float lt = atanhf(fminf(hn, CLIPV)) / hn;  // logmap0 scale
    s_m *= lt; s_b *= lt;
    ushort4 o;
    o.x = __half_as_ushort(__float2half(s_m * m.x + s_b * e0));
    o.y = __half_as_ushort(__float2half(s_m * m.y + s_b * e1));
    o.z = __half_as_ushort(__float2half(s_m * m.z + s_b * e2));
    o.w = __half_as_ushort(__float2half(s_m * m.w + s_b * e3));
    *(ushort4*)(XT + base) = o;
}

// ---- fused CSR aggregation + FULL finish: one wave per dst row ----
// agg = sum w*xt[src]; h=proj(expmap0(agg)); xt2=relu(logmap0(h));
// o = proj(expmap0(xt2))   <-- HypAct runs for EVERY layer (R8/R9 bug: it was
// skipped on the mid-layer path). Mid-layer: bf16(o) + |o|^2; final: fp32(o).
__global__ void k_agg_finish(const unsigned short* __restrict__ XT, const int* __restrict__ off,
                             const int* __restrict__ csrc, const float* __restrict__ cw,
                             float* __restrict__ OUT, unsigned short* __restrict__ OUT_bf,
                             float* __restrict__ hnorm2, int nrows) {
    int gid = blockIdx.x * blockDim.x + threadIdx.x;
    int row = gid >> 6, lane = gid & 63;
    if (row >= nrows) return;
    int p0 = off[row], p1 = off[row + 1];
    float a0 = 0.f, a1 = 0.f, a2 = 0.f, a3 = 0.f;
    int p = p0;
    for (; p + 3 < p1; p += 4) {
        int s0 = csrc[p], s1 = csrc[p + 1], s2 = csrc[p + 2], s3 = csrc[p + 3];
        float w0 = cw[p], w1 = cw[p + 1], w2 = cw[p + 2], w3 = cw[p + 3];
        ushort4 vA = *(const ushort4*)(XT + (size_t)s0 * DIM + lane * 4);
        ushort4 vB = *(const ushort4*)(XT + (size_t)s1 * DIM + lane * 4);
        ushort4 vC = *(const ushort4*)(XT + (size_t)s2 * DIM + lane * 4);
        ushort4 vD = *(const ushort4*)(XT + (size_t)s3 * DIM + lane * 4);
        a0 = fmaf(w0, h2f(vA.x), a0); a1 = fmaf(w0, h2f(vA.y), a1);
        a2 = fmaf(w0, h2f(vA.z), a2); a3 = fmaf(w0, h2f(vA.w), a3);
        a0 = fmaf(w1, h2f(vB.x), a0); a1 = fmaf(w1, h2f(vB.y), a1);
        a2 = fmaf(w1, h2f(vB.z), a2); a3 = fmaf(w1, h2f(vB.w), a3);
        a0 = fmaf(w2, h2f(vC.x), a0); a1 = fmaf(w2, h2f(vC.y), a1);
        a2 = fmaf(w2, h2f(vC.z), a2); a3 = fmaf(w2, h2f(vC.w), a3);
        a0 = fmaf(w3, h2f(vD.x), a0); a1 = fmaf(w3, h2f(vD.y), a1);
        a2 = fmaf(w3, h2f(vD.z), a2); a3 = fmaf(w3, h2f(vD.w), a3);
    }
    for (; p < p1; ++p) {
        int s = csrc[p];
        float w = cw[p];
        ushort4 v = *(const ushort4*)(XT + (size_t)s * DIM + lane * 4);
        a0 = fmaf(w, h2f(v.x), a0); a1 = fmaf(w, h2f(v.y), a1);
        a2 = fmaf(w, h2f(v.z), a2); a3 = fmaf(w, h2f(v.w), a3);
    }
    float ss = wsum(a0 * a0 + a1 * a1 + a2 * a2 + a3 * a3);
    float n = fmaxf(sqrtf(ss), MINN);
    float tn = tanhf(n);
    float hn = (tn > MAXNORM) ? MAXNORM : tn;
    float s1 = hn / n;                              // h = s1*agg
    float lt = atanhf(fminf(hn, CLIPV)) / fmaxf(hn, MINN);
    float s2 = lt * s1;                             // logmap0(h) = s2*agg
    float x0 = fmaxf(s2 * a0, 0.f), x1 = fmaxf(s2 * a1, 0.f);
    float x2 = fmaxf(s2 * a2, 0.f), x3 = fmaxf(s2 * a3, 0.f);
    float ss2 = wsum(x0 * x0 + x1 * x1 + x2 * x2 + x3 * x3);
    float n2 = fmaxf(sqrtf(ss2), MINN);
    float tn2 = tanhf(n2);
    float hn2c = (tn2 > MAXNORM) ? MAXNORM : tn2;
    float s3 = hn2c / n2;                           // o = s3 * relu(...)
    float o0 = s3 * x0, o1 = s3 * x1, o2 = s3 * x2, o3 = s3 * x3;
    size_t base = (size_t)row * DIM + lane * 4;
    if (OUT_bf) {                        // mid-layer: emit bf16 o + |o|^2
        ushort4 ob;
        ob.x = f2bf(o0); ob.y = f2bf(o1); ob.z = f2bf(o2); ob.w = f2bf(o3);
        *(ushort4*)(OUT_bf + base) = ob;
        if (lane == 0) hnorm2[row] = hn2c * hn2c;
    } else {                             // final layer: fp32 out
        *(float4*)(OUT + base) = make_float4(o0, o1, o2, o3);
    }
}

static inline size_t align256(size_t x) { return (x + 255) & ~(size_t)255; }

extern "C" void kernel_launch(void* const* d_in, const int* in_sizes, int n_in,
                              void* d_out, int out_size, void* d_ws, size_t ws_size,
                              hipStream_t stream) {
    const float* x  = (const float*)d_in[0];
    const float* W1 = (const float*)d_in[1];
    const float* b1 = (const float*)d_in[2];
    const float* W2 = (const float*)d_in[3];
    const float* b2 = (const float*)d_in[4];
    const float* ew = (const float*)d_in[5];
    const int* esrc = (const int*)d_in[6];
    const int* edst = (const int*)d_in[7];
    const int nE = in_sizes[5];
    const int M  = in_sizes[0] / DIM;   // 10000

    size_t S = (size_t)M * DIM;         // elements per N x D buffer
    char* base = (char*)d_ws;
    size_t o = 0;
    float* mx     = (float*)(base + o);          o = align256(o + S * 4);
    float* csr_w  = (float*)(base + o);          o = align256(o + (size_t)nE * 4);
    int* csr_off  = (int*)(base + o);            o = align256(o + (size_t)(M + 1) * 4);
    int* cursor   = (int*)(base + o);            o = align256(o + (size_t)M * 4);
    int* csr_src  = (int*)(base + o);            o = align256(o + (size_t)nE * 4);
    float* hnorm2 = (float*)(base + o);          o = align256(o + (size_t)(M + 64) * 4);
    unsigned short* xt   = (unsigned short*)(base + o);  o = align256(o + S * 2);
    unsigned short* h_bf = (unsigned short*)(base + o);  o = align256(o + S * 2);
    unsigned short* w_bf = (unsigned short*)(base + o);  o = align256(o + (size_t)2 * DIM * DIM * 2);

    int rowBlocks = (M + 3) / 4;        // 4 waves (rows) per 256-thread block
    dim3 gemmGrid(DIM / 16, (M + 63) / 64);
    int edgeBlocks = (nE + 255) / 256;

    // ---- build CSR by dst (edges are call-constant): 4 dispatches ----
    k_zero_int<<<64, 256, 0, stream>>>(csr_off, M + 1);
    k_hist<<<edgeBlocks, 256, 0, stream>>>(edst, csr_off, nE, M);
    k_scan<<<1, 1024, 0, stream>>>(csr_off, cursor, M + 1);
    k_fill<<<edgeBlocks, 256, 0, stream>>>(esrc, edst, ew, cursor, csr_src, csr_w, nE, M);

    // ---- weights to bf16 (both layers, one dispatch) ----
    k_cvt_bf16x2<<<256, 256, 0, stream>>>(W1, W2, w_bf, DIM * DIM);

    k_expmap_in<<<rowBlocks, 256, 0, stream>>>(x, h_bf, hnorm2, M);

    for (int layer = 0; layer < 2; ++layer) {
        const float* b = (layer == 0) ? b1 : b2;
        const unsigned short* Wb = w_bf + (size_t)layer * DIM * DIM;
        k_gemm_mfma<<<gemmGrid, 256, 0, stream>>>(h_bf, Wb, mx, M);
        k_post<<<rowBlocks, 256, 0, stream>>>(mx, hnorm2, b, xt, M);
        k_agg_finish<<<rowBlocks, 256, 0, stream>>>(
            xt, csr_off, csr_src, csr_w,
            (layer == 0) ? (float*)nullptr : (float*)d_out,
            (layer == 0) ? h_bf : (unsigned short*)nullptr,
            hnorm2, M);
    }
}